// Round 1
// baseline (658.331 us; speedup 1.0000x reference)
//
#include <hip/hip_runtime.h>

#define BB 16
#define TT 12
#define NN 10000
#define DD 2
#define EE 320000
#define BT (BB*TT)            // 192
#define TOT (BB*TT*NN*DD)     // 3,840,000

// ws layout: [0..4095] accumulators (float): [0]=main_sum [1]=spatial_sum
// [2]=temporal_sum [16..16+384)=cons partial sums. w2 packed array at +4096.

__global__ void pack_kernel(const float* __restrict__ p,
                            const float* __restrict__ tg,
                            float4* __restrict__ w2) {
    int i = blockIdx.x * blockDim.x + threadIdx.x;   // over BT*N = 1,920,000
    if (i >= BT * NN) return;
    int bt = i / NN;
    int n  = i - bt * NN;
    const float2 pv = *reinterpret_cast<const float2*>(p  + (size_t)i * 2);
    const float2 tv = *reinterpret_cast<const float2*>(tg + (size_t)i * 2);
    w2[(size_t)n * BT + bt] = make_float4(pv.x, pv.y, tv.x, tv.y);
}

// fused main (MAE) + temporal + conservation partial sums
__global__ void stream_kernel(const float* __restrict__ p,
                              const float* __restrict__ tg,
                              float* __restrict__ acc) {
    __shared__ float sc[BT * DD];      // 384 conservation keys
    __shared__ float sv[8], sw[8];
    for (int k = threadIdx.x; k < BT * DD; k += blockDim.x) sc[k] = 0.f;
    __syncthreads();

    int i = blockIdx.x * blockDim.x + threadIdx.x;   // exact grid: TOT threads
    float pv = p[i], tv = tg[i];
    float m = fabsf(pv - tv);

    int bt = i / (NN * DD);
    int tt = bt % TT;
    float w = 0.f;
    if (tt < TT - 1) {
        float pn = p[i + NN * DD], tn = tg[i + NN * DD];
        float dd = (pn - pv) - (tn - tv);
        w = dd * dd;
    }
    int key = bt * DD + (i & 1);
    atomicAdd(&sc[key], pv - tv);

    // block reduce m (main) and w (temporal)
    float v = m;
    for (int o = 32; o > 0; o >>= 1) { v += __shfl_down(v, o); w += __shfl_down(w, o); }
    int wid = threadIdx.x >> 6, lane = threadIdx.x & 63;
    if (lane == 0) { sv[wid] = v; sw[wid] = w; }
    __syncthreads();
    if (threadIdx.x == 0) {
        float a = 0.f, b = 0.f;
        int nw = blockDim.x >> 6;
        for (int k = 0; k < nw; k++) { a += sv[k]; b += sw[k]; }
        atomicAdd(&acc[0], a);
        atomicAdd(&acc[2], b);
    }
    // flush only touched conservation keys (skip exact zeros: identical result)
    for (int k = threadIdx.x; k < BT * DD; k += blockDim.x) {
        float s = sc[k];
        if (s != 0.f) atomicAdd(&acc[16 + k], s);
    }
}

// fast path: wave-per-edge, coalesced reads of packed per-node bt-streams
__global__ void spatial_packed(const float4* __restrict__ w2,
                               const int* __restrict__ idx,
                               float* __restrict__ acc) {
    __shared__ float sv[8];
    int lane   = threadIdx.x & 63;
    int wave   = (blockIdx.x * blockDim.x + threadIdx.x) >> 6;
    int nwaves = (gridDim.x * blockDim.x) >> 6;

    float s = 0.f;
    for (int e = wave; e < EE; e += nwaves) {
        int src = idx[e];
        int dst = idx[EE + e];
        const float4* S = w2 + (size_t)src * BT;
        const float4* Q = w2 + (size_t)dst * BT;
#pragma unroll
        for (int k = 0; k < 3; k++) {           // 3*64 = 192 = BT
            float4 a = S[lane + 64 * k];
            float4 b = Q[lane + 64 * k];
            float d0 = fabsf(a.x - b.x) - fabsf(a.z - b.z);
            float d1 = fabsf(a.y - b.y) - fabsf(a.w - b.w);
            s += d0 * d0 + d1 * d1;
        }
    }
    for (int o = 32; o > 0; o >>= 1) s += __shfl_down(s, o);
    int wid = threadIdx.x >> 6;
    if ((threadIdx.x & 63) == 0) sv[wid] = s;
    __syncthreads();
    if (threadIdx.x == 0) {
        float a = 0.f;
        int nw = blockDim.x >> 6;
        for (int k = 0; k < nw; k++) a += sv[k];
        atomicAdd(&acc[1], a);
    }
}

// fallback if workspace too small for the packed array
__global__ void spatial_fallback(const float* __restrict__ p,
                                 const float* __restrict__ tg,
                                 const int* __restrict__ idx,
                                 float* __restrict__ acc) {
    __shared__ float sv[8];
    int e = blockIdx.x * blockDim.x + threadIdx.x;
    float s = 0.f;
    if (e < EE) {
        int src = idx[e] * DD, dst = idx[EE + e] * DD;
        for (int bt = 0; bt < BT; bt++) {
            size_t base = (size_t)bt * NN * DD;
            float2 ps = *reinterpret_cast<const float2*>(p + base + src);
            float2 pd = *reinterpret_cast<const float2*>(p + base + dst);
            float2 ts = *reinterpret_cast<const float2*>(tg + base + src);
            float2 td = *reinterpret_cast<const float2*>(tg + base + dst);
            float d0 = fabsf(ps.x - pd.x) - fabsf(ts.x - td.x);
            float d1 = fabsf(ps.y - pd.y) - fabsf(ts.y - td.y);
            s += d0 * d0 + d1 * d1;
        }
    }
    for (int o = 32; o > 0; o >>= 1) s += __shfl_down(s, o);
    int wid = threadIdx.x >> 6;
    if ((threadIdx.x & 63) == 0) sv[wid] = s;
    __syncthreads();
    if (threadIdx.x == 0) {
        float a = 0.f;
        int nw = blockDim.x >> 6;
        for (int k = 0; k < nw; k++) a += sv[k];
        atomicAdd(&acc[1], a);
    }
}

__global__ void finalize_kernel(const float* __restrict__ acc,
                                float* __restrict__ out) {
    __shared__ float red[8];
    int tid = threadIdx.x;
    float v = 0.f;
    if (tid < BT * DD) { float c = acc[16 + tid]; v = c * c; }
    for (int o = 32; o > 0; o >>= 1) v += __shfl_down(v, o);
    if ((tid & 63) == 0) red[tid >> 6] = v;
    __syncthreads();
    if (tid == 0) {
        float cons = 0.f;
        int nw = (blockDim.x + 63) >> 6;
        for (int k = 0; k < nw; k++) cons += red[k];
        cons /= (float)(BT * DD);
        float mainl = acc[0] / (float)TOT;
        float spat  = acc[1] / ((float)BT * (float)EE * (float)DD);
        float temp  = acc[2] / ((float)BB * (TT - 1) * NN * DD);
        float total = mainl + 0.1f * spat + 0.05f * temp + 0.02f * cons;
        out[0] = total; out[1] = mainl; out[2] = spat; out[3] = temp; out[4] = cons;
    }
}

extern "C" void kernel_launch(void* const* d_in, const int* in_sizes, int n_in,
                              void* d_out, int out_size, void* d_ws, size_t ws_size,
                              hipStream_t stream) {
    const float* p  = (const float*)d_in[0];
    const float* tg = (const float*)d_in[1];
    const int*   ix = (const int*)d_in[2];
    float* out = (float*)d_out;
    float* acc = (float*)d_ws;

    hipMemsetAsync(d_ws, 0, 4096, stream);

    stream_kernel<<<TOT / 256, 256, 0, stream>>>(p, tg, acc);

    size_t w2_bytes = (size_t)NN * BT * sizeof(float4);   // 30,720,000
    if (ws_size >= 4096 + w2_bytes) {
        float4* w2 = (float4*)((char*)d_ws + 4096);
        pack_kernel<<<(BT * NN + 255) / 256, 256, 0, stream>>>(p, tg, w2);
        spatial_packed<<<2048, 256, 0, stream>>>(w2, ix, acc);
    } else {
        spatial_fallback<<<(EE + 255) / 256, 256, 0, stream>>>(p, tg, ix, acc);
    }

    finalize_kernel<<<1, 384, 0, stream>>>(acc, out);
}

// Round 2
// 109.477 us; speedup vs baseline: 6.0134x; 6.0134x over previous
//
#include <hip/hip_runtime.h>

#define BB 16
#define TT 12
#define NN 10000
#define DD 2
#define EE 320000
#define BT 192              // BB*TT
#define TOT 3840000         // BT*NN*DD
#define SLICE 20000         // NN*DD
#define PARTS 8
#define PART_SZ 2500        // SLICE/PARTS
#define SBLOCKS 1536        // BT*PARTS
#define SPATB 2048
#define CHUNK 32
#define NCHUNK 6            // BT/CHUNK

// ws float layout:
//   [0,1536)      main partials (per stream block)
//   [1536,3072)   temporal partials
//   [3072,6144)   cons partials (2 per stream block: even/odd d)
//   [6144,8192)   spatial partials (per spatial block)
//   byte 32768+   packed bf16 node array: ushort4 w2h[NN*BT]  (15.36 MB)

__device__ inline unsigned short f2b(float x) {          // RNE f32->bf16
    unsigned u = __float_as_uint(x);
    return (unsigned short)((u + 0x7FFFu + ((u >> 16) & 1u)) >> 16);
}
__device__ inline float b2f(unsigned short h) {
    return __uint_as_float((unsigned)h << 16);
}

// main(MAE) + temporal + conservation, zero atomics
__global__ __launch_bounds__(256) void stream_kernel(const float* __restrict__ p,
                                                     const float* __restrict__ tg,
                                                     float* __restrict__ ws) {
    int b = blockIdx.x;
    int bt = b >> 3, part = b & 7;
    int tt = bt % TT;
    size_t base = (size_t)bt * SLICE;
    bool inner = (tt < TT - 1);
    float m = 0.f, w = 0.f, c = 0.f;
    int j0 = part * PART_SZ;
    for (int j = j0 + threadIdx.x; j < j0 + PART_SZ; j += 256) {
        size_t jj = base + j;
        float pv = p[jj], tv = tg[jj];
        m += fabsf(pv - tv);
        c += pv - tv;                       // key parity = j&1 = tid&1 (strides even)
        if (inner) {
            float pn = p[jj + SLICE], tn = tg[jj + SLICE];
            float dd = (pn - pv) - (tn - tv);
            w += dd * dd;
        }
    }
    // m,w: full butterfly; c: parity-preserving (skip offset 1)
    for (int o = 32; o >= 2; o >>= 1) {
        m += __shfl_xor(m, o);
        w += __shfl_xor(w, o);
        c += __shfl_xor(c, o);
    }
    m += __shfl_xor(m, 1);
    w += __shfl_xor(w, 1);
    __shared__ float sm[4], sw[4], s0[4], s1[4];
    int wid = threadIdx.x >> 6, lane = threadIdx.x & 63;
    if (lane == 0) { sm[wid] = m; sw[wid] = w; s0[wid] = c; }
    if (lane == 1) { s1[wid] = c; }
    __syncthreads();
    if (threadIdx.x == 0) {
        float a = 0, bv = 0, c0 = 0, c1 = 0;
        for (int k = 0; k < 4; k++) { a += sm[k]; bv += sw[k]; c0 += s0[k]; c1 += s1[k]; }
        ws[b]            = a;
        ws[1536 + b]     = bv;
        ws[3072 + 2 * b]     = c0;
        ws[3072 + 2 * b + 1] = c1;
    }
}

// transpose-pack to bf16: w2h[n*BT + bt] = {p0,p1,t0,t1}, coalesced in and out
__global__ __launch_bounds__(256) void pack_kernel(const float* __restrict__ p,
                                                   const float* __restrict__ tg,
                                                   ushort4* __restrict__ w2h) {
    __shared__ ushort4 tile[32][BT + 1];
    int n0 = blockIdx.x * 32;
    int ln = threadIdx.x & 31;
    int r  = threadIdx.x >> 5;
    int n  = n0 + ln;
    if (n < NN) {
        for (int bt = r; bt < BT; bt += 8) {
            size_t e = (size_t)bt * SLICE + (size_t)n * 2;
            float2 pv = *reinterpret_cast<const float2*>(p + e);
            float2 tv = *reinterpret_cast<const float2*>(tg + e);
            tile[ln][bt] = make_ushort4(f2b(pv.x), f2b(pv.y), f2b(tv.x), f2b(tv.y));
        }
    }
    __syncthreads();
    int cnt = NN - n0; if (cnt > 32) cnt = 32;
    int total = cnt * BT;
    for (int e = threadIdx.x; e < total; e += 256) {
        int nn = e / BT, bt = e - nn * BT;
        w2h[(size_t)(n0 + nn) * BT + e - nn * BT] = tile[nn][bt];
    }
}

// chunked gather: per chunk, per-XCD resident set = 2.56MB nodes + 0.32MB edges < 4MB L2
__global__ __launch_bounds__(256) void spatial_kernel(const ushort4* __restrict__ w2h,
                                                      const int* __restrict__ idx,
                                                      float* __restrict__ ws) {
    int lane = threadIdx.x & 63;
    int esub = lane >> 5;                 // 2 edges per wave-iter
    int bts  = lane & 31;                 // bt slot within chunk
    int wave = (blockIdx.x * 256 + threadIdx.x) >> 6;
    const int stride = SPATB * 4 * 2;     // 16384
    float s = 0.f;
    for (int ch = 0; ch < NCHUNK; ++ch) {
        int c0 = ch * CHUNK;
        for (int eb = wave * 2; eb < EE; eb += stride) {
            int e  = eb + esub;
            int sn = idx[e];
            int dn = idx[EE + e];
            ushort4 a = w2h[(size_t)sn * BT + c0 + bts];
            ushort4 b = w2h[(size_t)dn * BT + c0 + bts];
            float d0 = fabsf(b2f(a.x) - b2f(b.x)) - fabsf(b2f(a.z) - b2f(b.z));
            float d1 = fabsf(b2f(a.y) - b2f(b.y)) - fabsf(b2f(a.w) - b2f(b.w));
            s = fmaf(d0, d0, s);
            s = fmaf(d1, d1, s);
        }
    }
    for (int o = 32; o; o >>= 1) s += __shfl_xor(s, o);
    __shared__ float sv[4];
    if (lane == 0) sv[threadIdx.x >> 6] = s;
    __syncthreads();
    if (threadIdx.x == 0) ws[6144 + blockIdx.x] = sv[0] + sv[1] + sv[2] + sv[3];
}

// fallback (ws too small for packed array): direct fp32 gather, per-block partials
__global__ __launch_bounds__(256) void spatial_fb(const float* __restrict__ p,
                                                  const float* __restrict__ tg,
                                                  const int* __restrict__ idx,
                                                  float* __restrict__ ws) {
    int lane = threadIdx.x & 63;
    int wave = (blockIdx.x * 256 + threadIdx.x) >> 6;
    float s = 0.f;
    for (int e = wave; e < EE; e += SPATB * 4) {
        int sn = idx[e] * DD, dn = idx[EE + e] * DD;
        for (int bt = lane; bt < BT; bt += 64) {
            size_t base = (size_t)bt * SLICE;
            float2 ps = *reinterpret_cast<const float2*>(p + base + sn);
            float2 pd = *reinterpret_cast<const float2*>(p + base + dn);
            float2 ts = *reinterpret_cast<const float2*>(tg + base + sn);
            float2 td = *reinterpret_cast<const float2*>(tg + base + dn);
            float d0 = fabsf(ps.x - pd.x) - fabsf(ts.x - td.x);
            float d1 = fabsf(ps.y - pd.y) - fabsf(ts.y - td.y);
            s = fmaf(d0, d0, s);
            s = fmaf(d1, d1, s);
        }
    }
    for (int o = 32; o; o >>= 1) s += __shfl_xor(s, o);
    __shared__ float sv[4];
    if (lane == 0) sv[threadIdx.x >> 6] = s;
    __syncthreads();
    if (threadIdx.x == 0) ws[6144 + blockIdx.x] = sv[0] + sv[1] + sv[2] + sv[3];
}

__global__ __launch_bounds__(1024) void finalize_kernel(const float* __restrict__ ws,
                                                        float* __restrict__ out) {
    int tid = threadIdx.x;
    float a = 0, bv = 0, sp = 0, cq = 0;
    for (int k = tid; k < SBLOCKS; k += 1024) { a += ws[k]; bv += ws[1536 + k]; }
    for (int k = tid; k < SPATB;   k += 1024) sp += ws[6144 + k];
    for (int k = tid; k < BT * DD; k += 1024) {          // 384 cons keys
        int bt = k >> 1, par = k & 1;
        float cs = 0;
        for (int part = 0; part < PARTS; ++part)
            cs += ws[3072 + ((bt * PARTS + part) << 1) + par];
        cq += cs * cs;
    }
    for (int o = 32; o; o >>= 1) {
        a  += __shfl_xor(a, o);  bv += __shfl_xor(bv, o);
        sp += __shfl_xor(sp, o); cq += __shfl_xor(cq, o);
    }
    __shared__ float ra[16], rb[16], rs[16], rc[16];
    int wid = tid >> 6;
    if ((tid & 63) == 0) { ra[wid] = a; rb[wid] = bv; rs[wid] = sp; rc[wid] = cq; }
    __syncthreads();
    if (tid == 0) {
        float A = 0, B2 = 0, S = 0, C = 0;
        for (int k = 0; k < 16; k++) { A += ra[k]; B2 += rb[k]; S += rs[k]; C += rc[k]; }
        float mainl = A / (float)TOT;
        float temp  = B2 / (float)(BB * (TT - 1) * NN * DD);
        float spat  = S / ((float)BT * (float)EE * (float)DD);
        float cons  = C / (float)(BT * DD);
        out[0] = mainl + 0.1f * spat + 0.05f * temp + 0.02f * cons;
        out[1] = mainl; out[2] = spat; out[3] = temp; out[4] = cons;
    }
}

extern "C" void kernel_launch(void* const* d_in, const int* in_sizes, int n_in,
                              void* d_out, int out_size, void* d_ws, size_t ws_size,
                              hipStream_t stream) {
    const float* p  = (const float*)d_in[0];
    const float* tg = (const float*)d_in[1];
    const int*   ix = (const int*)d_in[2];
    float* out = (float*)d_out;
    float* ws  = (float*)d_ws;

    stream_kernel<<<SBLOCKS, 256, 0, stream>>>(p, tg, ws);

    size_t need = 32768 + (size_t)NN * BT * sizeof(ushort4);
    if (ws_size >= need) {
        ushort4* w2h = (ushort4*)((char*)d_ws + 32768);
        pack_kernel<<<(NN + 31) / 32, 256, 0, stream>>>(p, tg, w2h);
        spatial_kernel<<<SPATB, 256, 0, stream>>>(w2h, ix, ws);
    } else {
        spatial_fb<<<SPATB, 256, 0, stream>>>(p, tg, ix, ws);
    }

    finalize_kernel<<<1, 1024, 0, stream>>>(ws, out);
}

// Round 3
// 92.561 us; speedup vs baseline: 7.1124x; 1.1828x over previous
//
#include <hip/hip_runtime.h>
#include <hip/hip_fp16.h>

#define BB 16
#define TT 12
#define NN 10000
#define DD 2
#define EE 320000
#define BT 192              // BB*TT
#define TOT 3840000         // BT*NN*DD
#define SLICE 20000         // NN*DD
#define PARTS 8
#define PART_SZ 2500        // SLICE/PARTS
#define SBLOCKS 1536        // BT*PARTS
#define SPATB 2048
#define NWAVES 8192         // SPATB*4
#define EPW 40              // edges per wave
#define E2 327680           // NWAVES*EPW (padded edge count)
#define CHUNK 32
#define NCHUNK 6            // BT/CHUNK
#define PACKB 313           // ceil(NN/32)

// ws float layout:
//   [0,1536)      main partials          [1536,3072) temporal partials
//   [3072,6144)   cons partials (2/blk)  [6144,8192) spatial partials
//   byte 32768+                 : ushort4 w2h[NN*BT]   (15.36 MB, fp16 packed)
//   byte 32768+NN*BT*8+         : uint2 eoff[E2]       (2.62 MB, byte offsets)

__device__ inline unsigned short f2h(float x) {
    return __half_as_ushort(__float2half(x));
}
__device__ inline __half2 u2h2(unsigned u) {
    __half2 r;
    *reinterpret_cast<unsigned*>(&r) = u;
    return r;
}

// ---------------- stream: main(MAE) + temporal + conservation (unchanged) ----
__global__ __launch_bounds__(256) void stream_kernel(const float* __restrict__ p,
                                                     const float* __restrict__ tg,
                                                     float* __restrict__ ws) {
    int b = blockIdx.x;
    int bt = b >> 3, part = b & 7;
    int tt = bt % TT;
    size_t base = (size_t)bt * SLICE;
    bool inner = (tt < TT - 1);
    float m = 0.f, w = 0.f, c = 0.f;
    int j0 = part * PART_SZ;
    for (int j = j0 + threadIdx.x; j < j0 + PART_SZ; j += 256) {
        size_t jj = base + j;
        float pv = p[jj], tv = tg[jj];
        m += fabsf(pv - tv);
        c += pv - tv;                       // key parity = j&1 = tid&1
        if (inner) {
            float pn = p[jj + SLICE], tn = tg[jj + SLICE];
            float dd = (pn - pv) - (tn - tv);
            w += dd * dd;
        }
    }
    for (int o = 32; o >= 2; o >>= 1) {
        m += __shfl_xor(m, o);
        w += __shfl_xor(w, o);
        c += __shfl_xor(c, o);
    }
    m += __shfl_xor(m, 1);
    w += __shfl_xor(w, 1);
    __shared__ float sm[4], sw[4], s0[4], s1[4];
    int wid = threadIdx.x >> 6, lane = threadIdx.x & 63;
    if (lane == 0) { sm[wid] = m; sw[wid] = w; s0[wid] = c; }
    if (lane == 1) { s1[wid] = c; }
    __syncthreads();
    if (threadIdx.x == 0) {
        float a = 0, bv = 0, c0 = 0, c1 = 0;
        for (int k = 0; k < 4; k++) { a += sm[k]; bv += sw[k]; c0 += s0[k]; c1 += s1[k]; }
        ws[b]            = a;
        ws[1536 + b]     = bv;
        ws[3072 + 2 * b]     = c0;
        ws[3072 + 2 * b + 1] = c1;
    }
}

// ---------------- pack (fp16) + edge-offset precompute, one launch ----------
__global__ __launch_bounds__(256) void prep_kernel(const float* __restrict__ p,
                                                   const float* __restrict__ tg,
                                                   const int* __restrict__ idx,
                                                   ushort4* __restrict__ w2h,
                                                   uint2* __restrict__ eoff) {
    __shared__ ushort4 tile[32][BT + 1];
    if (blockIdx.x < PACKB) {
        int n0 = blockIdx.x * 32;
        int ln = threadIdx.x & 31;
        int r  = threadIdx.x >> 5;
        int n  = n0 + ln;
        if (n < NN) {
            for (int bt = r; bt < BT; bt += 8) {
                size_t e = (size_t)bt * SLICE + (size_t)n * 2;
                float2 pv = *reinterpret_cast<const float2*>(p + e);
                float2 tv = *reinterpret_cast<const float2*>(tg + e);
                tile[ln][bt] = make_ushort4(f2h(pv.x), f2h(pv.y), f2h(tv.x), f2h(tv.y));
            }
        }
        __syncthreads();
        int cnt = NN - n0; if (cnt > 32) cnt = 32;
        int total = cnt * BT;
        for (int e = threadIdx.x; e < total; e += 256) {
            int nn = e / BT, bt = e - nn * BT;
            w2h[(size_t)(n0 + nn) * BT + bt] = tile[nn][bt];
        }
    } else {
        int e = (blockIdx.x - PACKB) * 256 + threadIdx.x;   // [0, E2)
        if (e < E2) {
            uint2 v = make_uint2(0u, 0u);
            if (e < EE)
                v = make_uint2((unsigned)idx[e] * 1536u, (unsigned)idx[EE + e] * 1536u);
            eoff[e] = v;
        }
    }
}

// ---------------- spatial: chunked gather, unroll x4, fp16 packed math ------
__global__ __launch_bounds__(256) void spatial_kernel(const char* __restrict__ w2,
                                                      const uint2* __restrict__ eoff,
                                                      float* __restrict__ ws) {
    int lane = threadIdx.x & 63;
    int esub = lane >> 5;                 // which of the 2 edges this half-wave owns
    int bts  = lane & 31;                 // bt slot within the chunk
    int wave = (blockIdx.x * 256 + threadIdx.x) >> 6;
    const uint2* ep = eoff + wave * EPW + esub;   // this wave's 40-edge span

    float s = 0.f;
    for (int ch = 0; ch < NCHUNK; ++ch) {
        int cbo = ch * (CHUNK * 8) + bts * 8;     // byte offset within a node row
#pragma unroll
        for (int g = 0; g < 5; ++g) {
            uint2 o[4], av[4], bv[4];
#pragma unroll
            for (int u = 0; u < 4; ++u) o[u] = ep[(g * 4 + u) * 2];
#pragma unroll
            for (int u = 0; u < 4; ++u) {
                av[u] = *reinterpret_cast<const uint2*>(w2 + o[u].x + cbo);
                bv[u] = *reinterpret_cast<const uint2*>(w2 + o[u].y + cbo);
            }
#pragma unroll
            for (int u = 0; u < 4; ++u) {
                __half2 pd = __habs2(__hsub2(u2h2(av[u].x), u2h2(bv[u].x)));
                __half2 td = __habs2(__hsub2(u2h2(av[u].y), u2h2(bv[u].y)));
                float2 f = __half22float2(__hsub2(pd, td));
                s = fmaf(f.x, f.x, s);
                s = fmaf(f.y, f.y, s);
            }
        }
    }
    for (int o = 32; o; o >>= 1) s += __shfl_xor(s, o);
    __shared__ float sv[4];
    if (lane == 0) sv[threadIdx.x >> 6] = s;
    __syncthreads();
    if (threadIdx.x == 0) ws[6144 + blockIdx.x] = sv[0] + sv[1] + sv[2] + sv[3];
}

// ---------------- fallback (ws too small): direct fp32 gather ---------------
__global__ __launch_bounds__(256) void spatial_fb(const float* __restrict__ p,
                                                  const float* __restrict__ tg,
                                                  const int* __restrict__ idx,
                                                  float* __restrict__ ws) {
    int lane = threadIdx.x & 63;
    int wave = (blockIdx.x * 256 + threadIdx.x) >> 6;
    float s = 0.f;
    for (int e = wave; e < EE; e += SPATB * 4) {
        int sn = idx[e] * DD, dn = idx[EE + e] * DD;
        for (int bt = lane; bt < BT; bt += 64) {
            size_t base = (size_t)bt * SLICE;
            float2 ps = *reinterpret_cast<const float2*>(p + base + sn);
            float2 pd = *reinterpret_cast<const float2*>(p + base + dn);
            float2 ts = *reinterpret_cast<const float2*>(tg + base + sn);
            float2 td = *reinterpret_cast<const float2*>(tg + base + dn);
            float d0 = fabsf(ps.x - pd.x) - fabsf(ts.x - td.x);
            float d1 = fabsf(ps.y - pd.y) - fabsf(ts.y - td.y);
            s = fmaf(d0, d0, s);
            s = fmaf(d1, d1, s);
        }
    }
    for (int o = 32; o; o >>= 1) s += __shfl_xor(s, o);
    __shared__ float sv[4];
    if (lane == 0) sv[threadIdx.x >> 6] = s;
    __syncthreads();
    if (threadIdx.x == 0) ws[6144 + blockIdx.x] = sv[0] + sv[1] + sv[2] + sv[3];
}

// ---------------- finalize (unchanged) --------------------------------------
__global__ __launch_bounds__(1024) void finalize_kernel(const float* __restrict__ ws,
                                                        float* __restrict__ out) {
    int tid = threadIdx.x;
    float a = 0, bv = 0, sp = 0, cq = 0;
    for (int k = tid; k < SBLOCKS; k += 1024) { a += ws[k]; bv += ws[1536 + k]; }
    for (int k = tid; k < SPATB;   k += 1024) sp += ws[6144 + k];
    for (int k = tid; k < BT * DD; k += 1024) {
        int bt = k >> 1, par = k & 1;
        float cs = 0;
        for (int part = 0; part < PARTS; ++part)
            cs += ws[3072 + ((bt * PARTS + part) << 1) + par];
        cq += cs * cs;
    }
    for (int o = 32; o; o >>= 1) {
        a  += __shfl_xor(a, o);  bv += __shfl_xor(bv, o);
        sp += __shfl_xor(sp, o); cq += __shfl_xor(cq, o);
    }
    __shared__ float ra[16], rb[16], rs[16], rc[16];
    int wid = tid >> 6;
    if ((tid & 63) == 0) { ra[wid] = a; rb[wid] = bv; rs[wid] = sp; rc[wid] = cq; }
    __syncthreads();
    if (tid == 0) {
        float A = 0, B2 = 0, S = 0, C = 0;
        for (int k = 0; k < 16; k++) { A += ra[k]; B2 += rb[k]; S += rs[k]; C += rc[k]; }
        float mainl = A / (float)TOT;
        float temp  = B2 / (float)(BB * (TT - 1) * NN * DD);
        float spat  = S / ((float)BT * (float)EE * (float)DD);
        float cons  = C / (float)(BT * DD);
        out[0] = mainl + 0.1f * spat + 0.05f * temp + 0.02f * cons;
        out[1] = mainl; out[2] = spat; out[3] = temp; out[4] = cons;
    }
}

extern "C" void kernel_launch(void* const* d_in, const int* in_sizes, int n_in,
                              void* d_out, int out_size, void* d_ws, size_t ws_size,
                              hipStream_t stream) {
    const float* p  = (const float*)d_in[0];
    const float* tg = (const float*)d_in[1];
    const int*   ix = (const int*)d_in[2];
    float* out = (float*)d_out;
    float* ws  = (float*)d_ws;

    stream_kernel<<<SBLOCKS, 256, 0, stream>>>(p, tg, ws);

    size_t w2_bytes = (size_t)NN * BT * sizeof(ushort4);       // 15,360,000
    size_t need = 32768 + w2_bytes + (size_t)E2 * sizeof(uint2);
    if (ws_size >= need) {
        char*  w2b  = (char*)d_ws + 32768;
        uint2* eoff = (uint2*)(w2b + w2_bytes);
        int eblocks = (E2 + 255) / 256;                        // 1280
        prep_kernel<<<PACKB + eblocks, 256, 0, stream>>>(p, tg, ix,
                                                         (ushort4*)w2b, eoff);
        spatial_kernel<<<SPATB, 256, 0, stream>>>(w2b, eoff, ws);
    } else {
        spatial_fb<<<SPATB, 256, 0, stream>>>(p, tg, ix, ws);
    }

    finalize_kernel<<<1, 1024, 0, stream>>>(ws, out);
}